// Round 5
// baseline (270.327 us; speedup 1.0000x reference)
//
#include <hip/hip_runtime.h>

// out[bt, i, d] = x[bt, i] * W[i, d] + b[i, d]
// B=64, P=2000, D=512, all float32.
//
// R9: R8 + NONTEMPORAL stores. Model status after R4/R6/R7/R8:
//   - Four different store patterns (4MB x4 fronts, 4MB lockstep, 8MB flat
//     asc, 8MB flat desc) ALL give kernel-window ~100 us (~2.6 TB/s demand)
//     for 271 MB compulsory + <=256 MB inherited poison drain.
//   - Byte conservation: fill's own window is HBM-saturated (1.049 GB @
//     6.55 TB/s). Drain-inclusive kernel budget is ~80 us; pipelined ideal
//     ~45 us. We sit at 100.
//   - Surviving mechanism: at kernel entry L3 is 100% dirty poison (fill =
//     4x L3 capacity, poison region is 4x out's size => disjoint buffer,
//     which is why R8's dirty-harvest was null). Plain store-allocates are
//     gated by dirty-victim writeback rate => ~40% of ceiling.
// Lever: __builtin_nontemporal_store bypasses L3 allocation; our stream
// stops waiting on evictions and goes straight to the HBM write queues.
// Prior session's nt regression was measured in the fragmented R4
// structure, before this mechanism was identified; re-test under the
// single-front structure with ONE change vs R8's 262.0 us.
// Predicted: kernel window 100 -> ~80-85, dur 262 -> ~240-248.
// Null/regress => revert to R8, declare roofline (fill 160 saturated +
// drain-gated kernel window ~= 240-260 structural).

typedef float fx4 __attribute__((ext_vector_type(4)));

#define P_DIM    2000
#define SLICE    256000u            // fx4 per bt-slice (4 MB)
#define STRIDE2  512000u            // 2 slices = 8 MB window
#define NTHREADS 256
#define NBLOCKS  (STRIDE2 / NTHREADS)   // 2000 blocks, all co-resident
#define NITER    32                 // 32 windows cover B*P*D4 exactly

__global__ __launch_bounds__(256) void FeatureExpander_49185965473877_kernel(
    const float* __restrict__ x,   // (B, P)
    const fx4* __restrict__ W,     // (P, D/4)
    const fx4* __restrict__ b,     // (P, D/4)
    fx4* __restrict__ out)         // (B, P, D/4) flat
{
    unsigned n0 = blockIdx.x * NTHREADS + threadIdx.x;   // < 512000
    unsigned wb = n0 >= SLICE ? n0 - SLICE : n0;         // i*128 + d4, invariant

    fx4 wv = W[wb];                 // read once per thread
    fx4 bv = b[wb];

    // Highest window first, walk down (R8 direction, proven neutral).
    const float* xp = x + (n0 >> 7) + (NITER - 1) * 2 * P_DIM;
    fx4* op = out + n0 + (unsigned)(NITER - 1) * STRIDE2;

#pragma unroll 2
    for (int it = 0; it < NITER; ++it) {
        float xv = *xp;
        fx4 o;
        o.x = fmaf(xv, wv.x, bv.x);
        o.y = fmaf(xv, wv.y, bv.y);
        o.z = fmaf(xv, wv.z, bv.z);
        o.w = fmaf(xv, wv.w, bv.w);
        __builtin_nontemporal_store(o, op);   // bypass L3 allocate-vs-dirty stall
        xp -= 2 * P_DIM;            // bt -= 2
        op -= STRIDE2;              // previous 8 MB window
    }
}

extern "C" void kernel_launch(void* const* d_in, const int* in_sizes, int n_in,
                              void* d_out, int out_size, void* d_ws, size_t ws_size,
                              hipStream_t stream) {
    const float* x = (const float*)d_in[0];
    const fx4*   W = (const fx4*)d_in[1];
    const fx4*   b = (const fx4*)d_in[2];
    fx4* out = (fx4*)d_out;

    FeatureExpander_49185965473877_kernel<<<NBLOCKS, NTHREADS, 0, stream>>>(x, W, b, out);
}

// Round 6
// 262.724 us; speedup vs baseline: 1.0289x; 1.0289x over previous
//
#include <hip/hip_runtime.h>

// out[bt, i, d] = x[bt, i] * W[i, d] + b[i, d]
// B=64, P=2000, D=512, all float32.
//
// R10 = R8 FINAL (revert of R9's nontemporal experiment, which regressed
// 262.0 -> 270.3 and killed the L3 allocate-stall model).
//
// Session conclusion — why this is the floor:
//   Timed graph = harness poison-fill (1.049 GB, HBM-saturated at
//   6.3-6.6 TB/s = ~160-168 us, WRITE_SIZE proves full HBM transit) +
//   kernel window (~100 us). Kernel window budget: 271 MB compulsory
//   (43 us at ceiling) + ~256 MB of the fill's L3 dirty residue draining
//   through the same HBM write queues during our window (~40 us) + ramp.
//   Five independent structures (4MB x4 fronts / 4MB lockstep / 8MB flat
//   asc / 8MB flat desc / W/b-reload), plain vs nt stores, 1000-2048
//   blocks: all land 262-273 us. The residual is the harness's bytes,
//   not ours.
//
// Structure: each thread owns one (i,d4) column; W/b read exactly once
// into 8 VGPRs (8.7 MB total reads). 2000 blocks sweep 32 x 8 MB windows
// in descending order, one 16 B store per thread per window (1 KB/wave
// contiguous). unroll 2 = two outstanding write streams per wave.

typedef float fx4 __attribute__((ext_vector_type(4)));

#define P_DIM    2000
#define SLICE    256000u            // fx4 per bt-slice (4 MB)
#define STRIDE2  512000u            // 2 slices = 8 MB window
#define NTHREADS 256
#define NBLOCKS  (STRIDE2 / NTHREADS)   // 2000 blocks, all co-resident
#define NITER    32                 // 32 windows cover B*P*D4 exactly

__global__ __launch_bounds__(256) void FeatureExpander_49185965473877_kernel(
    const float* __restrict__ x,   // (B, P)
    const fx4* __restrict__ W,     // (P, D/4)
    const fx4* __restrict__ b,     // (P, D/4)
    fx4* __restrict__ out)         // (B, P, D/4) flat
{
    unsigned n0 = blockIdx.x * NTHREADS + threadIdx.x;   // < 512000
    unsigned wb = n0 >= SLICE ? n0 - SLICE : n0;         // i*128 + d4, invariant

    fx4 wv = W[wb];                 // read once per thread
    fx4 bv = b[wb];

    // Highest window first, walk down (direction measured neutral; desc
    // was the best-measured variant).
    const float* xp = x + (n0 >> 7) + (NITER - 1) * 2 * P_DIM;
    fx4* op = out + n0 + (unsigned)(NITER - 1) * STRIDE2;

#pragma unroll 2
    for (int it = 0; it < NITER; ++it) {
        float xv = *xp;
        fx4 o;
        o.x = fmaf(xv, wv.x, bv.x);
        o.y = fmaf(xv, wv.y, bv.y);
        o.z = fmaf(xv, wv.z, bv.z);
        o.w = fmaf(xv, wv.w, bv.w);
        *op = o;                    // plain store: 1 KB/wave contiguous
        xp -= 2 * P_DIM;            // bt -= 2
        op -= STRIDE2;              // previous 8 MB window
    }
}

extern "C" void kernel_launch(void* const* d_in, const int* in_sizes, int n_in,
                              void* d_out, int out_size, void* d_ws, size_t ws_size,
                              hipStream_t stream) {
    const float* x = (const float*)d_in[0];
    const fx4*   W = (const fx4*)d_in[1];
    const fx4*   b = (const fx4*)d_in[2];
    fx4* out = (fx4*)d_out;

    FeatureExpander_49185965473877_kernel<<<NBLOCKS, NTHREADS, 0, stream>>>(x, W, b, out);
}